// Round 7
// baseline (44.248 us; speedup 1.0000x reference)
//
#include <hip/hip_runtime.h>
#include <math.h>

// Problem constants
#define BB 512      // batch (edges)
#define NN 4096     // nodes
#define LL 128      // feature dim
#define IN_DIM 385  // 3*L + ND
#define IN_PAD 388  // padded to multiple of 4
#define NK4_1 97    // ceil(IN_DIM/4) k-groups for layer 1
#define EPB 2       // edges per block (edge kernel)
#define GPB 4       // nodes per block (gru kernel)

// ---------------------------------------------------------------------------
// Workspace layout (float offsets)
// ---------------------------------------------------------------------------
#define OFF_MSG   0                          // msg_sum (N*L), zeroed by prep
#define OFF_CNT   (OFF_MSG + NN * LL)        // cnt (N), zeroed by prep
#define OFF_COUNT (OFF_CNT + NN)             // seen_count (1 int) + pad
#define OFF_LIST  (OFF_COUNT + 4)            // seen list (1024 ints)
#define OFF_W1PS  (OFF_LIST + 1024)          // src w1 packed f4[k4*LL + j]
#define OFF_W1PT  (OFF_W1PS + NK4_1 * LL * 4)
// end ~ 2.5 MB

// ---------------------------------------------------------------------------
// Prep: pack layer-1 weights (row stride 385 is odd -> needs repack for
// float4) + zero msg_sum/cnt/count. w2/wih/whh are read directly later
// (their rows are 16B-aligned). ~3.7 MB total traffic.
// ---------------------------------------------------------------------------
__global__ __launch_bounds__(256) void prep_kernel(
    const float* __restrict__ sw1, const float* __restrict__ tw1,
    float* __restrict__ ws)
{
    const int i = blockIdx.x * 256 + threadIdx.x;
    const int stride = gridDim.x * 256;

    float4* msg4 = (float4*)(ws + OFF_MSG);
    const float4 z4 = make_float4(0.f, 0.f, 0.f, 0.f);
    for (int idx = i; idx < NN * LL / 4; idx += stride)
        msg4[idx] = z4;
    for (int idx = i; idx < NN; idx += stride)
        ws[OFF_CNT + idx] = 0.0f;
    if (i == 0)
        ((int*)ws)[OFF_COUNT] = 0;

    float4* w1ps = (float4*)(ws + OFF_W1PS);
    float4* w1pt = (float4*)(ws + OFF_W1PT);
    for (int idx = i; idx < NK4_1 * LL; idx += stride) {
        const int k4 = idx >> 7, j = idx & 127;
        const int k = k4 * 4;
        float4 a, b;
        a.x = sw1[j * IN_DIM + k];     b.x = tw1[j * IN_DIM + k];
        a.y = (k + 1 < IN_DIM) ? sw1[j * IN_DIM + k + 1] : 0.f;
        b.y = (k + 1 < IN_DIM) ? tw1[j * IN_DIM + k + 1] : 0.f;
        a.z = (k + 2 < IN_DIM) ? sw1[j * IN_DIM + k + 2] : 0.f;
        b.z = (k + 2 < IN_DIM) ? tw1[j * IN_DIM + k + 2] : 0.f;
        a.w = (k + 3 < IN_DIM) ? sw1[j * IN_DIM + k + 3] : 0.f;
        b.w = (k + 3 < IN_DIM) ? tw1[j * IN_DIM + k + 3] : 0.f;
        w1ps[idx] = a; w1pt[idx] = b;
    }
}

// ---------------------------------------------------------------------------
// Edge messages: 512 threads/block, one block = one side of EPB=2 edges.
// 4-way k-split halves each wave's serial load chain vs r5 (2-way/256thr),
// doubling waves/CU for latency hiding. Blocks >= 512: memory->out copy.
// ---------------------------------------------------------------------------
__global__ __launch_bounds__(512) void edge_msg_kernel(
    const float* __restrict__ x,        // (B, N, 1)
    const float* __restrict__ memory,   // (N, L)
    const float* __restrict__ delta_t,  // (B, N, L)
    const float* __restrict__ sb1, const float* __restrict__ sw2,
    const float* __restrict__ sb2,
    const float* __restrict__ tb1, const float* __restrict__ tw2,
    const float* __restrict__ tb2,
    const int* __restrict__ source, const int* __restrict__ target,
    float* __restrict__ ws, float* __restrict__ out)
{
    const int tid = threadIdx.x;

    // ---- copy blocks (16 x 512 threads) ----
    if (blockIdx.x >= 512) {
        const int cb = blockIdx.x - 512;
        float4* out4 = (float4*)out;
        const float4* mem4 = (const float4*)memory;
        for (int idx = cb * 512 + tid; idx < NN * LL / 4; idx += 16 * 512)
            out4[idx] = mem4[idx];
        return;
    }

    // ---- edge blocks ----
    const int side  = blockIdx.x & 1;
    const int chunk = blockIdx.x >> 1;       // 0 .. 255
    const int g     = tid >> 7;              // k-split group 0..3
    const int j     = tid & 127;             // output feature

    __shared__ float in2[IN_PAD][EPB];
    __shared__ float h1[LL][EPB];
    __shared__ float part1[4][EPB][LL];
    __shared__ float part2[4][EPB][LL];
    __shared__ int   node_sh[EPB];

    const float4* w1p = (const float4*)(ws + (side ? OFF_W1PT : OFF_W1PS));
    const float* w2  = side ? tw2 : sw2;
    const float* b1  = side ? tb1 : sb1;
    const float* b2  = side ? tb2 : sb2;

    // Stage EPB edges' input vectors (pad -> 0).
    #pragma unroll
    for (int e = 0; e < EPB; ++e) {
        const int eg = chunk * EPB + e;
        const int s = source[eg], t = target[eg];
        const int node  = side ? t : s;
        const int other = side ? s : t;
        if (tid == 0) node_sh[e] = node;
        for (int idx = tid; idx < IN_PAD; idx += 512) {
            float v = 0.0f;
            if (idx < LL)           v = memory[node * LL + idx];
            else if (idx < 2 * LL)  v = memory[other * LL + (idx - LL)];
            else if (idx < 3 * LL)  v = delta_t[((size_t)eg * NN + node) * LL + (idx - 2 * LL)];
            else if (idx == 3 * LL) v = x[(size_t)eg * NN + node];
            in2[idx][e] = v;
        }
    }
    __syncthreads();

    // Layer 1 (packed w1), 4-way k4 split: [0,25) [25,49) [49,73) [73,97)
    {
        const int k40 = (g == 0) ? 0 : (g == 1) ? 25 : (g == 2) ? 49 : 73;
        const int k41 = (g == 0) ? 25 : (g == 1) ? 49 : (g == 2) ? 73 : 97;
        float a0 = 0.f, a1 = 0.f;
        #pragma unroll 5
        for (int k4 = k40; k4 < k41; ++k4) {
            const float4 w  = w1p[k4 * LL + j];
            const float4 i0 = *(const float4*)&in2[k4 * 4][0];
            const float4 i1 = *(const float4*)&in2[k4 * 4 + 2][0];
            a0 = fmaf(w.x, i0.x, a0); a1 = fmaf(w.x, i0.y, a1);
            a0 = fmaf(w.y, i0.z, a0); a1 = fmaf(w.y, i0.w, a1);
            a0 = fmaf(w.z, i1.x, a0); a1 = fmaf(w.z, i1.y, a1);
            a0 = fmaf(w.w, i1.z, a0); a1 = fmaf(w.w, i1.w, a1);
        }
        part1[g][0][j] = a0;
        part1[g][1][j] = a1;
    }
    __syncthreads();

    // Combine + bias + relu; groups 0,1 finish edges 0,1.
    if (g < EPB) {
        const int e = g;
        const float v = part1[0][e][j] + part1[1][e][j]
                      + part1[2][e][j] + part1[3][e][j] + b1[j];
        h1[j][e] = fmaxf(v, 0.0f);
    }
    __syncthreads();

    // Layer 2 (direct w2, 16B-aligned rows), 4-way k split: g*32 .. g*32+32
    {
        const int k0 = g * 32;
        float a0 = 0.f, a1 = 0.f;
        #pragma unroll 4
        for (int i = 0; i < 8; ++i) {
            const int k = k0 + 4 * i;
            const float4 w  = *(const float4*)&w2[j * LL + k];
            const float4 hA = *(const float4*)&h1[k][0];
            const float4 hB = *(const float4*)&h1[k + 2][0];
            a0 = fmaf(w.x, hA.x, a0); a1 = fmaf(w.x, hA.y, a1);
            a0 = fmaf(w.y, hA.z, a0); a1 = fmaf(w.y, hA.w, a1);
            a0 = fmaf(w.z, hB.x, a0); a1 = fmaf(w.z, hB.y, a1);
            a0 = fmaf(w.w, hB.z, a0); a1 = fmaf(w.w, hB.w, a1);
        }
        part2[g][0][j] = a0;
        part2[g][1][j] = a1;
    }
    __syncthreads();

    // Final message; atomic segment-sum. Groups 0,1 finish edges 0,1.
    if (g < EPB) {
        const int e = g;
        const float m = part2[0][e][j] + part2[1][e][j]
                      + part2[2][e][j] + part2[3][e][j] + b2[j];
        atomicAdd(ws + OFF_MSG + node_sh[e] * LL + j, m);
    }
    if (tid < EPB) {
        const int node = node_sh[tid];
        const float old = atomicAdd(ws + OFF_CNT + node, 1.0f);
        if (old == 0.0f) {
            const int pos = atomicAdd((int*)ws + OFF_COUNT, 1);
            ((int*)ws)[OFF_LIST + pos] = node;
        }
    }
}

// ---------------------------------------------------------------------------
// GRU over the compact seen list. GPB=4 nodes/block, 256 blocks, 512 threads.
// 4-way split: gsel = g>>1 (0: wih vs agg, 1: whh vs h), khalf = g&1
// (k in [khalf*64, khalf*64+64)). Direct 16B-aligned weight reads.
// ---------------------------------------------------------------------------
__global__ __launch_bounds__(512) void gru_kernel(
    const float* __restrict__ memory,
    const float* __restrict__ wih, const float* __restrict__ whh,
    const float* __restrict__ bih, const float* __restrict__ bhh,
    float* __restrict__ ws, float* __restrict__ out)
{
    const int tid = threadIdx.x;
    const int g = tid >> 7, j = tid & 127;
    const int scount = ((const int*)ws)[OFF_COUNT];
    const int base = blockIdx.x * GPB;
    if (base >= scount) return;
    const int nact = min(GPB, scount - base);

    __shared__ float ah[LL][2 * GPB];        // [k][slot] 0..3=agg, 4..7=h
    __shared__ float gpart[4][3][GPB][LL];   // [group][gate][slot][j]  24 KB
    __shared__ int   nodes_sh[GPB];

    if (tid < GPB)
        nodes_sh[tid] = (base + tid < scount)
                        ? ((const int*)ws)[OFF_LIST + base + tid] : -1;
    __syncthreads();

    // Stage agg (group 0) and h (group 1), coalesced over j.
    if (g < 2) {
        #pragma unroll
        for (int s = 0; s < GPB; ++s) {
            const int node = nodes_sh[s];
            if (g == 0) {
                float v = 0.0f;
                if (node >= 0) {
                    const float c = ws[OFF_CNT + node];
                    v = ws[OFF_MSG + node * LL + j] / c;
                }
                ah[j][s] = v;
            } else {
                ah[j][GPB + s] = (node >= 0) ? memory[node * LL + j] : 0.0f;
            }
        }
    }
    __syncthreads();

    // Matvec quarter: operand gsel (0=agg/wih, 1=h/whh), k-half khalf.
    {
        const int gsel = g >> 1, khalf = g & 1;
        const float* wmat = gsel ? whh : wih;
        float a0[GPB] = {}, a1[GPB] = {}, a2[GPB] = {};
        const int k40 = khalf * 16;
        #pragma unroll 2
        for (int k4 = k40; k4 < k40 + 16; ++k4) {
            const float4 w0 = *(const float4*)&wmat[(0 * LL + j) * LL + 4 * k4];
            const float4 w1 = *(const float4*)&wmat[(1 * LL + j) * LL + 4 * k4];
            const float4 w2 = *(const float4*)&wmat[(2 * LL + j) * LL + 4 * k4];
            const float w0a[4] = {w0.x, w0.y, w0.z, w0.w};
            const float w1a[4] = {w1.x, w1.y, w1.z, w1.w};
            const float w2a[4] = {w2.x, w2.y, w2.z, w2.w};
            #pragma unroll
            for (int c = 0; c < 4; ++c) {
                const float4 v4 = *(const float4*)&ah[k4 * 4 + c][gsel * GPB];
                const float va[4] = {v4.x, v4.y, v4.z, v4.w};
                #pragma unroll
                for (int s = 0; s < GPB; ++s) {
                    a0[s] = fmaf(w0a[c], va[s], a0[s]);
                    a1[s] = fmaf(w1a[c], va[s], a1[s]);
                    a2[s] = fmaf(w2a[c], va[s], a2[s]);
                }
            }
        }
        #pragma unroll
        for (int s = 0; s < GPB; ++s) {
            gpart[g][0][s][j] = a0[s];
            gpart[g][1][s][j] = a1[s];
            gpart[g][2][s][j] = a2[s];
        }
    }
    __syncthreads();

    // Finalize: combine k-halves of each operand's gates.
    const int total = nact * LL;
    for (int o = tid; o < total; o += 512) {
        const int s = o >> 7, jj = o & 127;
        const int node = nodes_sh[s];
        const float ir = gpart[0][0][s][jj] + gpart[1][0][s][jj] + bih[jj];
        const float iz = gpart[0][1][s][jj] + gpart[1][1][s][jj] + bih[LL + jj];
        const float inn = gpart[0][2][s][jj] + gpart[1][2][s][jj] + bih[2 * LL + jj];
        const float hr = gpart[2][0][s][jj] + gpart[3][0][s][jj] + bhh[jj];
        const float hz = gpart[2][1][s][jj] + gpart[3][1][s][jj] + bhh[LL + jj];
        const float hn = gpart[2][2][s][jj] + gpart[3][2][s][jj] + bhh[2 * LL + jj];
        const float r = 1.0f / (1.0f + __expf(-(ir + hr)));
        const float z = 1.0f / (1.0f + __expf(-(iz + hz)));
        const float n = tanhf(inn + r * hn);
        const float h = ah[jj][GPB + s];
        out[node * LL + jj] = (1.0f - z) * n + z * h;
    }
}

// ---------------------------------------------------------------------------
extern "C" void kernel_launch(void* const* d_in, const int* in_sizes, int n_in,
                              void* d_out, int out_size, void* d_ws, size_t ws_size,
                              hipStream_t stream) {
    const float* x        = (const float*)d_in[0];
    const float* memory   = (const float*)d_in[1];
    const float* delta_t  = (const float*)d_in[2];
    const float* src_w1   = (const float*)d_in[3];
    const float* src_b1   = (const float*)d_in[4];
    const float* src_w2   = (const float*)d_in[5];
    const float* src_b2   = (const float*)d_in[6];
    const float* tar_w1   = (const float*)d_in[7];
    const float* tar_b1   = (const float*)d_in[8];
    const float* tar_w2   = (const float*)d_in[9];
    const float* tar_b2   = (const float*)d_in[10];
    const float* gru_wih  = (const float*)d_in[11];
    const float* gru_whh  = (const float*)d_in[12];
    const float* gru_bih  = (const float*)d_in[13];
    const float* gru_bhh  = (const float*)d_in[14];
    const int*   source   = (const int*)d_in[15];
    const int*   target   = (const int*)d_in[16];

    float* out = (float*)d_out;
    float* ws  = (float*)d_ws;

    // 1) pack w1 + zero accumulators
    prep_kernel<<<256, 256, 0, stream>>>(src_w1, tar_w1, ws);

    // 2) edge messages (512 blocks x 512 thr) + memory->out copy (16 blocks)
    edge_msg_kernel<<<528, 512, 0, stream>>>(
        x, memory, delta_t,
        src_b1, src_w2, src_b2, tar_b1, tar_w2, tar_b2,
        source, target, ws, out);

    // 3) GRU over compact seen list (256 blocks x 512 thr)
    gru_kernel<<<1024 / GPB, 512, 0, stream>>>(
        memory, gru_wih, gru_whh, gru_bih, gru_bhh, ws, out);
}

// Round 8
// 37.113 us; speedup vs baseline: 1.1923x; 1.1923x over previous
//
#include <hip/hip_runtime.h>
#include <math.h>

// Problem constants
#define BB 512      // batch (edges)
#define NN 4096     // nodes
#define LL 128      // feature dim
#define IN_DIM 385  // 3*L + ND
#define IN_PAD 388  // padded to multiple of 4
#define NK4_1 97    // ceil(IN_DIM/4) k-groups, layer 1
#define NK4_2 32    // LL/4 k-groups, layer 2 / GRU
#define EPB 2       // edges per block (edge kernel)
#define GPB 4       // nodes per block (gru kernel)

// ---------------------------------------------------------------------------
// Workspace layout (float offsets, float4-aligned)
// ---------------------------------------------------------------------------
#define OFF_MSG   0                           // msg_sum (N*L)
#define OFF_CNT   (OFF_MSG + NN * LL)         // cnt (N)
#define OFF_COUNT (OFF_CNT + NN)              // seen_count (1 int) + pad
#define OFF_LIST  (OFF_COUNT + 4)             // seen list (1024 ints)
#define OFF_W1PS  529416                      // src_w1 packed f4[k4*128+j]
#define OFF_W1PT  (OFF_W1PS + NK4_1 * LL * 4)
#define OFF_W2PS  (OFF_W1PT + NK4_1 * LL * 4)
#define OFF_W2PT  (OFF_W2PS + NK4_2 * LL * 4)
#define OFF_WIHP  (OFF_W2PT + NK4_2 * LL * 4) // f4[(gate*32+k4)*128+j]
#define OFF_WHHP  (OFF_WIHP + 3 * NK4_2 * LL * 4)

// ---------------------------------------------------------------------------
// Prep: zero accumulators + pack ALL weights as f4[k4*128 + j] (lane-
// coalesced: consecutive j = consecutive addresses). NO copy here (moved to
// edge kernel's extra blocks, off the critical path).
// ---------------------------------------------------------------------------
__global__ __launch_bounds__(256) void prep_kernel(
    const float* __restrict__ sw1, const float* __restrict__ tw1,
    const float* __restrict__ sw2, const float* __restrict__ tw2,
    const float* __restrict__ wih, const float* __restrict__ whh,
    float* __restrict__ ws)
{
    const int i = blockIdx.x * 256 + threadIdx.x;
    const int stride = gridDim.x * 256;

    float4* msg4 = (float4*)(ws + OFF_MSG);
    const float4 z4 = make_float4(0.f, 0.f, 0.f, 0.f);
    for (int idx = i; idx < NN * LL / 4; idx += stride)
        msg4[idx] = z4;
    for (int idx = i; idx < NN; idx += stride)
        ws[OFF_CNT + idx] = 0.0f;
    if (i == 0)
        ((int*)ws)[OFF_COUNT] = 0;

    // layer-1: (L, IN) -> f4 w1p[k4*L + j] = w1[j][4k4..4k4+3], zero-padded
    float4* w1ps = (float4*)(ws + OFF_W1PS);
    float4* w1pt = (float4*)(ws + OFF_W1PT);
    for (int idx = i; idx < NK4_1 * LL; idx += stride) {
        const int k4 = idx >> 7, j = idx & 127;
        const int k = k4 * 4;
        float4 a, b;
        a.x = sw1[j * IN_DIM + k];     b.x = tw1[j * IN_DIM + k];
        a.y = (k + 1 < IN_DIM) ? sw1[j * IN_DIM + k + 1] : 0.f;
        b.y = (k + 1 < IN_DIM) ? tw1[j * IN_DIM + k + 1] : 0.f;
        a.z = (k + 2 < IN_DIM) ? sw1[j * IN_DIM + k + 2] : 0.f;
        b.z = (k + 2 < IN_DIM) ? tw1[j * IN_DIM + k + 2] : 0.f;
        a.w = (k + 3 < IN_DIM) ? sw1[j * IN_DIM + k + 3] : 0.f;
        b.w = (k + 3 < IN_DIM) ? tw1[j * IN_DIM + k + 3] : 0.f;
        w1ps[idx] = a; w1pt[idx] = b;
    }
    // layer-2: (L, L) -> f4 w2p[k4*L + j]
    float4* w2ps = (float4*)(ws + OFF_W2PS);
    float4* w2pt = (float4*)(ws + OFF_W2PT);
    for (int idx = i; idx < NK4_2 * LL; idx += stride) {
        const int k4 = idx >> 7, j = idx & 127;
        const int k = k4 * 4;
        w2ps[idx] = make_float4(sw2[j * LL + k], sw2[j * LL + k + 1],
                                sw2[j * LL + k + 2], sw2[j * LL + k + 3]);
        w2pt[idx] = make_float4(tw2[j * LL + k], tw2[j * LL + k + 1],
                                tw2[j * LL + k + 2], tw2[j * LL + k + 3]);
    }
    // GRU: (3L, L) -> f4 wp[(gate*32+k4)*L + j] = w[gate*128+j][4k4..]
    float4* wihp = (float4*)(ws + OFF_WIHP);
    float4* whhp = (float4*)(ws + OFF_WHHP);
    for (int idx = i; idx < 3 * NK4_2 * LL; idx += stride) {
        const int j = idx & 127;
        const int gk = idx >> 7;            // gate*32 + k4
        const int gate = gk >> 5, k4 = gk & 31;
        const int row = gate * LL + j, k = k4 * 4;
        wihp[idx] = make_float4(wih[row * LL + k], wih[row * LL + k + 1],
                                wih[row * LL + k + 2], wih[row * LL + k + 3]);
        whhp[idx] = make_float4(whh[row * LL + k], whh[row * LL + k + 1],
                                whh[row * LL + k + 2], whh[row * LL + k + 3]);
    }
}

// ---------------------------------------------------------------------------
// Edge messages: blocks 0..511 = one side of EPB=2 edges (r5-proven body);
// blocks 512..543 = memory->out passthrough copy (parallel with edge work).
// ---------------------------------------------------------------------------
__global__ __launch_bounds__(256) void edge_msg_kernel(
    const float* __restrict__ x,        // (B, N, 1)
    const float* __restrict__ memory,   // (N, L)
    const float* __restrict__ delta_t,  // (B, N, L)
    const float* __restrict__ sb1, const float* __restrict__ sb2,
    const float* __restrict__ tb1, const float* __restrict__ tb2,
    const int* __restrict__ source, const int* __restrict__ target,
    float* __restrict__ ws, float* __restrict__ out)
{
    const int tid = threadIdx.x;

    // ---- copy blocks ----
    if (blockIdx.x >= 512) {
        const int cb = blockIdx.x - 512;
        float4* out4 = (float4*)out;
        const float4* mem4 = (const float4*)memory;
        for (int idx = cb * 256 + tid; idx < NN * LL / 4; idx += 32 * 256)
            out4[idx] = mem4[idx];
        return;
    }

    // ---- edge blocks ----
    const int side  = blockIdx.x & 1;
    const int chunk = blockIdx.x >> 1;
    const int g     = tid >> 7;
    const int j     = tid & 127;

    __shared__ float in2[IN_PAD][EPB];
    __shared__ float h1[LL][EPB];
    __shared__ float part1[2][EPB][LL];
    __shared__ float part2[2][EPB][LL];
    __shared__ int   node_sh[EPB];

    const float4* w1p = (const float4*)(ws + (side ? OFF_W1PT : OFF_W1PS));
    const float4* w2p = (const float4*)(ws + (side ? OFF_W2PT : OFF_W2PS));
    const float* b1  = side ? tb1 : sb1;
    const float* b2  = side ? tb2 : sb2;

    #pragma unroll
    for (int e = 0; e < EPB; ++e) {
        const int eg = chunk * EPB + e;
        const int s = source[eg], t = target[eg];
        const int node  = side ? t : s;
        const int other = side ? s : t;
        if (tid == 0) node_sh[e] = node;
        for (int idx = tid; idx < IN_PAD; idx += 256) {
            float v = 0.0f;
            if (idx < LL)           v = memory[node * LL + idx];
            else if (idx < 2 * LL)  v = memory[other * LL + (idx - LL)];
            else if (idx < 3 * LL)  v = delta_t[((size_t)eg * NN + node) * LL + (idx - 2 * LL)];
            else if (idx == 3 * LL) v = x[(size_t)eg * NN + node];
            in2[idx][e] = v;
        }
    }
    __syncthreads();

    // Layer 1: g0 -> k4 [0,49), g1 -> [49,97)
    {
        const int k40 = g ? 49 : 0;
        const int k41 = g ? NK4_1 : 49;
        float a0 = 0.f, a1 = 0.f;
        #pragma unroll 4
        for (int k4 = k40; k4 < k41; ++k4) {
            const float4 w  = w1p[k4 * LL + j];
            const float4 i0 = *(const float4*)&in2[k4 * 4][0];
            const float4 i1 = *(const float4*)&in2[k4 * 4 + 2][0];
            a0 = fmaf(w.x, i0.x, a0); a1 = fmaf(w.x, i0.y, a1);
            a0 = fmaf(w.y, i0.z, a0); a1 = fmaf(w.y, i0.w, a1);
            a0 = fmaf(w.z, i1.x, a0); a1 = fmaf(w.z, i1.y, a1);
            a0 = fmaf(w.w, i1.z, a0); a1 = fmaf(w.w, i1.w, a1);
        }
        part1[g][0][j] = a0;
        part1[g][1][j] = a1;
    }
    __syncthreads();

    h1[j][g] = fmaxf(part1[0][g][j] + part1[1][g][j] + b1[j], 0.0f);
    __syncthreads();

    // Layer 2: g0 -> k4 [0,16), g1 -> [16,32)
    {
        const int k40 = g * 16, k41 = k40 + 16;
        float a0 = 0.f, a1 = 0.f;
        #pragma unroll 4
        for (int k4 = k40; k4 < k41; ++k4) {
            const float4 w  = w2p[k4 * LL + j];
            const float4 h0 = *(const float4*)&h1[k4 * 4][0];
            const float4 h2 = *(const float4*)&h1[k4 * 4 + 2][0];
            a0 = fmaf(w.x, h0.x, a0); a1 = fmaf(w.x, h0.y, a1);
            a0 = fmaf(w.y, h0.z, a0); a1 = fmaf(w.y, h0.w, a1);
            a0 = fmaf(w.z, h2.x, a0); a1 = fmaf(w.z, h2.y, a1);
            a0 = fmaf(w.w, h2.z, a0); a1 = fmaf(w.w, h2.w, a1);
        }
        part2[g][0][j] = a0;
        part2[g][1][j] = a1;
    }
    __syncthreads();

    {
        const float m = part2[0][g][j] + part2[1][g][j] + b2[j];
        atomicAdd(ws + OFF_MSG + node_sh[g] * LL + j, m);
    }
    if (tid < EPB) {
        const int node = node_sh[tid];
        const float old = atomicAdd(ws + OFF_CNT + node, 1.0f);
        if (old == 0.0f) {
            const int pos = atomicAdd((int*)ws + OFF_COUNT, 1);
            ((int*)ws)[OFF_LIST + pos] = node;
        }
    }
}

// ---------------------------------------------------------------------------
// GRU over the compact seen list. GPB=4 nodes/block, 256 blocks, gate-split,
// packed (lane-coalesced) weights.
// ---------------------------------------------------------------------------
__global__ __launch_bounds__(256) void gru_kernel(
    const float* __restrict__ memory,
    const float* __restrict__ bih, const float* __restrict__ bhh,
    float* __restrict__ ws, float* __restrict__ out)
{
    const int tid = threadIdx.x;
    const int g = tid >> 7, j = tid & 127;
    const int scount = ((const int*)ws)[OFF_COUNT];
    const int base = blockIdx.x * GPB;
    if (base >= scount) return;
    const int nact = min(GPB, scount - base);

    __shared__ float ah[LL][2 * GPB];        // [k][slot] 0..3=agg, 4..7=h
    __shared__ float gates[6][GPB][LL];
    __shared__ int   nodes_sh[GPB];

    if (tid < GPB)
        nodes_sh[tid] = (base + tid < scount)
                        ? ((const int*)ws)[OFF_LIST + base + tid] : -1;
    __syncthreads();

    #pragma unroll
    for (int gi = 0; gi < GPB; ++gi) {
        const int node = nodes_sh[gi];
        if (g == 0) {
            float v = 0.0f;
            if (node >= 0) {
                const float c = ws[OFF_CNT + node];
                v = ws[OFF_MSG + node * LL + j] / c;
            }
            ah[j][gi] = v;
        } else {
            ah[j][GPB + gi] = (node >= 0) ? memory[node * LL + j] : 0.0f;
        }
    }
    __syncthreads();

    const float4* wp = (const float4*)(ws + (g ? OFF_WHHP : OFF_WIHP));
    float a0[GPB] = {}, a1[GPB] = {}, a2[GPB] = {};
    #pragma unroll 2
    for (int k4 = 0; k4 < NK4_2; ++k4) {
        const float4 w0 = wp[(0 * NK4_2 + k4) * LL + j];
        const float4 w1 = wp[(1 * NK4_2 + k4) * LL + j];
        const float4 w2 = wp[(2 * NK4_2 + k4) * LL + j];
        const float w0a[4] = {w0.x, w0.y, w0.z, w0.w};
        const float w1a[4] = {w1.x, w1.y, w1.z, w1.w};
        const float w2a[4] = {w2.x, w2.y, w2.z, w2.w};
        #pragma unroll
        for (int c = 0; c < 4; ++c) {
            const float4 v4 = *(const float4*)&ah[k4 * 4 + c][g * GPB];
            const float va[4] = {v4.x, v4.y, v4.z, v4.w};
            #pragma unroll
            for (int gi = 0; gi < GPB; ++gi) {
                a0[gi] = fmaf(w0a[c], va[gi], a0[gi]);
                a1[gi] = fmaf(w1a[c], va[gi], a1[gi]);
                a2[gi] = fmaf(w2a[c], va[gi], a2[gi]);
            }
        }
    }
    #pragma unroll
    for (int gi = 0; gi < GPB; ++gi) {
        gates[g * 3 + 0][gi][j] = a0[gi];
        gates[g * 3 + 1][gi][j] = a1[gi];
        gates[g * 3 + 2][gi][j] = a2[gi];
    }
    __syncthreads();

    const int total = nact * LL;
    for (int o = tid; o < total; o += 256) {
        const int gi = o >> 7, jj = o & 127;
        const int node = nodes_sh[gi];
        const float ir = gates[0][gi][jj] + bih[jj];
        const float iz = gates[1][gi][jj] + bih[LL + jj];
        const float inn = gates[2][gi][jj] + bih[2 * LL + jj];
        const float hr = gates[3][gi][jj] + bhh[jj];
        const float hz = gates[4][gi][jj] + bhh[LL + jj];
        const float hn = gates[5][gi][jj] + bhh[2 * LL + jj];
        const float r = 1.0f / (1.0f + __expf(-(ir + hr)));
        const float z = 1.0f / (1.0f + __expf(-(iz + hz)));
        const float n = tanhf(inn + r * hn);
        const float h = ah[jj][GPB + gi];
        out[node * LL + jj] = (1.0f - z) * n + z * h;
    }
}

// ---------------------------------------------------------------------------
extern "C" void kernel_launch(void* const* d_in, const int* in_sizes, int n_in,
                              void* d_out, int out_size, void* d_ws, size_t ws_size,
                              hipStream_t stream) {
    const float* x        = (const float*)d_in[0];
    const float* memory   = (const float*)d_in[1];
    const float* delta_t  = (const float*)d_in[2];
    const float* src_w1   = (const float*)d_in[3];
    const float* src_b1   = (const float*)d_in[4];
    const float* src_w2   = (const float*)d_in[5];
    const float* src_b2   = (const float*)d_in[6];
    const float* tar_w1   = (const float*)d_in[7];
    const float* tar_b1   = (const float*)d_in[8];
    const float* tar_w2   = (const float*)d_in[9];
    const float* tar_b2   = (const float*)d_in[10];
    const float* gru_wih  = (const float*)d_in[11];
    const float* gru_whh  = (const float*)d_in[12];
    const float* gru_bih  = (const float*)d_in[13];
    const float* gru_bhh  = (const float*)d_in[14];
    const int*   source   = (const int*)d_in[15];
    const int*   target   = (const int*)d_in[16];

    float* out = (float*)d_out;
    float* ws  = (float*)d_ws;

    // 1) prep: zero accumulators + pack all weights (no copy)
    prep_kernel<<<512, 256, 0, stream>>>(
        src_w1, tar_w1, src_w2, tar_w2, gru_wih, gru_whh, ws);

    // 2) edge messages (512 blocks) + memory->out copy (32 blocks)
    edge_msg_kernel<<<544, 256, 0, stream>>>(
        x, memory, delta_t, src_b1, src_b2, tar_b1, tar_b2,
        source, target, ws, out);

    // 3) GRU over compact seen list
    gru_kernel<<<1024 / GPB, 256, 0, stream>>>(
        memory, gru_bih, gru_bhh, ws, out);
}

// Round 9
// 35.684 us; speedup vs baseline: 1.2400x; 1.0400x over previous
//
#include <hip/hip_runtime.h>
#include <math.h>

// Problem constants
#define BB 512      // batch (edges)
#define NN 4096     // nodes
#define LL 128      // feature dim
#define IN_DIM 385  // 3*L + ND
#define NK4_1 97    // ceil(IN_DIM/4) k-groups, layer 1
#define NK4_2 32    // LL/4 k-groups, layer 2 / GRU
#define EPB 2       // edges per block (edge kernel)
#define GPB 4       // nodes per block (gru kernel)

// ---------------------------------------------------------------------------
// Workspace layout (float offsets, float4-aligned)
// ---------------------------------------------------------------------------
#define OFF_MSG   0                           // msg_sum (N*L)
#define OFF_CNT   (OFF_MSG + NN * LL)         // cnt (N)
#define OFF_COUNT (OFF_CNT + NN)              // seen_count (1 int) + pad
#define OFF_LIST  (OFF_COUNT + 4)             // seen list (1024 ints)
#define OFF_W1PS  529416                      // src_w1 packed f4[k4*128+j]
#define OFF_W1PT  (OFF_W1PS + NK4_1 * LL * 4)
#define OFF_W2PS  (OFF_W1PT + NK4_1 * LL * 4)
#define OFF_W2PT  (OFF_W2PS + NK4_2 * LL * 4)
#define OFF_WIHP  (OFF_W2PT + NK4_2 * LL * 4) // f4[(gate*32+k4)*128+j]
#define OFF_WHHP  (OFF_WIHP + 3 * NK4_2 * LL * 4)

// ---------------------------------------------------------------------------
// Prep: zero accumulators + pack ALL weights as f4[k4*128 + j] (lane-
// coalesced). Identical to r8 (proven).
// ---------------------------------------------------------------------------
__global__ __launch_bounds__(256) void prep_kernel(
    const float* __restrict__ sw1, const float* __restrict__ tw1,
    const float* __restrict__ sw2, const float* __restrict__ tw2,
    const float* __restrict__ wih, const float* __restrict__ whh,
    float* __restrict__ ws)
{
    const int i = blockIdx.x * 256 + threadIdx.x;
    const int stride = gridDim.x * 256;

    float4* msg4 = (float4*)(ws + OFF_MSG);
    const float4 z4 = make_float4(0.f, 0.f, 0.f, 0.f);
    for (int idx = i; idx < NN * LL / 4; idx += stride)
        msg4[idx] = z4;
    for (int idx = i; idx < NN; idx += stride)
        ws[OFF_CNT + idx] = 0.0f;
    if (i == 0)
        ((int*)ws)[OFF_COUNT] = 0;

    float4* w1ps = (float4*)(ws + OFF_W1PS);
    float4* w1pt = (float4*)(ws + OFF_W1PT);
    for (int idx = i; idx < NK4_1 * LL; idx += stride) {
        const int k4 = idx >> 7, j = idx & 127;
        const int k = k4 * 4;
        float4 a, b;
        a.x = sw1[j * IN_DIM + k];     b.x = tw1[j * IN_DIM + k];
        a.y = (k + 1 < IN_DIM) ? sw1[j * IN_DIM + k + 1] : 0.f;
        b.y = (k + 1 < IN_DIM) ? tw1[j * IN_DIM + k + 1] : 0.f;
        a.z = (k + 2 < IN_DIM) ? sw1[j * IN_DIM + k + 2] : 0.f;
        b.z = (k + 2 < IN_DIM) ? tw1[j * IN_DIM + k + 2] : 0.f;
        a.w = (k + 3 < IN_DIM) ? sw1[j * IN_DIM + k + 3] : 0.f;
        b.w = (k + 3 < IN_DIM) ? tw1[j * IN_DIM + k + 3] : 0.f;
        w1ps[idx] = a; w1pt[idx] = b;
    }
    float4* w2ps = (float4*)(ws + OFF_W2PS);
    float4* w2pt = (float4*)(ws + OFF_W2PT);
    for (int idx = i; idx < NK4_2 * LL; idx += stride) {
        const int k4 = idx >> 7, j = idx & 127;
        const int k = k4 * 4;
        w2ps[idx] = make_float4(sw2[j * LL + k], sw2[j * LL + k + 1],
                                sw2[j * LL + k + 2], sw2[j * LL + k + 3]);
        w2pt[idx] = make_float4(tw2[j * LL + k], tw2[j * LL + k + 1],
                                tw2[j * LL + k + 2], tw2[j * LL + k + 3]);
    }
    float4* wihp = (float4*)(ws + OFF_WIHP);
    float4* whhp = (float4*)(ws + OFF_WHHP);
    for (int idx = i; idx < 3 * NK4_2 * LL; idx += stride) {
        const int j = idx & 127;
        const int gk = idx >> 7;
        const int gate = gk >> 5, k4 = gk & 31;
        const int row = gate * LL + j, k = k4 * 4;
        wihp[idx] = make_float4(wih[row * LL + k], wih[row * LL + k + 1],
                                wih[row * LL + k + 2], wih[row * LL + k + 3]);
        whhp[idx] = make_float4(whh[row * LL + k], whh[row * LL + k + 1],
                                whh[row * LL + k + 2], whh[row * LL + k + 3]);
    }
}

// ---------------------------------------------------------------------------
// Edge messages: blocks 0..511 = one side of 2 edges; blocks 512..543 copy
// memory->out. NO input staging: layer-1 inputs are read at BLOCK-UNIFORM
// scalar addresses (s_load path, K$), segment-split so each loop streams one
// source array. Layer-2 keeps small h1 LDS broadcast.
// ---------------------------------------------------------------------------
__global__ __launch_bounds__(256) void edge_msg_kernel(
    const float* __restrict__ x,        // (B, N, 1)
    const float* __restrict__ memory,   // (N, L)
    const float* __restrict__ delta_t,  // (B, N, L)
    const float* __restrict__ sb1, const float* __restrict__ sb2,
    const float* __restrict__ tb1, const float* __restrict__ tb2,
    const int* __restrict__ source, const int* __restrict__ target,
    float* __restrict__ ws, float* __restrict__ out)
{
    const int tid = threadIdx.x;

    // ---- copy blocks ----
    if (blockIdx.x >= 512) {
        const int cb = blockIdx.x - 512;
        float4* out4 = (float4*)out;
        const float4* mem4 = (const float4*)memory;
        for (int idx = cb * 256 + tid; idx < NN * LL / 4; idx += 32 * 256)
            out4[idx] = mem4[idx];
        return;
    }

    // ---- edge blocks ----
    const int side  = blockIdx.x & 1;
    const int chunk = blockIdx.x >> 1;
    const int g     = tid >> 7;              // segment-split group
    const int j     = tid & 127;             // output feature

    const int eg0 = chunk * EPB, eg1 = eg0 + 1;
    const int s0 = source[eg0], t0 = target[eg0];
    const int s1 = source[eg1], t1 = target[eg1];
    const int node0  = side ? t0 : s0, other0 = side ? s0 : t0;
    const int node1  = side ? t1 : s1, other1 = side ? s1 : t1;

    __shared__ float h1[LL][EPB];
    __shared__ float part1[2][EPB][LL];
    __shared__ float part2[2][EPB][LL];

    const float4* w1p = (const float4*)(ws + (side ? OFF_W1PT : OFF_W1PS));
    const float4* w2p = (const float4*)(ws + (side ? OFF_W2PT : OFF_W2PS));
    const float* b1  = side ? tb1 : sb1;
    const float* b2  = side ? tb2 : sb2;

    // Layer 1, segment-split: g0 -> mem[node] (k4 0..31) + dt[0..15];
    //                         g1 -> mem[other] (k4 32..63) + dt[16..31] + x.
    {
        float a0 = 0.f, a1 = 0.f;
        const float* dA = delta_t + ((size_t)eg0 * NN + node0) * LL;
        const float* dB = delta_t + ((size_t)eg1 * NN + node1) * LL;
        if (g == 0) {
            const float* pA = memory + (size_t)node0 * LL;
            const float* pB = memory + (size_t)node1 * LL;
            #pragma unroll 4
            for (int k4 = 0; k4 < 32; ++k4) {
                const float4 w  = w1p[k4 * LL + j];
                const float4 iA = *(const float4*)(pA + 4 * k4);
                const float4 iB = *(const float4*)(pB + 4 * k4);
                a0 = fmaf(w.x, iA.x, a0); a1 = fmaf(w.x, iB.x, a1);
                a0 = fmaf(w.y, iA.y, a0); a1 = fmaf(w.y, iB.y, a1);
                a0 = fmaf(w.z, iA.z, a0); a1 = fmaf(w.z, iB.z, a1);
                a0 = fmaf(w.w, iA.w, a0); a1 = fmaf(w.w, iB.w, a1);
            }
            #pragma unroll 4
            for (int k4 = 64; k4 < 80; ++k4) {
                const float4 w  = w1p[k4 * LL + j];
                const float4 iA = *(const float4*)(dA + 4 * (k4 - 64));
                const float4 iB = *(const float4*)(dB + 4 * (k4 - 64));
                a0 = fmaf(w.x, iA.x, a0); a1 = fmaf(w.x, iB.x, a1);
                a0 = fmaf(w.y, iA.y, a0); a1 = fmaf(w.y, iB.y, a1);
                a0 = fmaf(w.z, iA.z, a0); a1 = fmaf(w.z, iB.z, a1);
                a0 = fmaf(w.w, iA.w, a0); a1 = fmaf(w.w, iB.w, a1);
            }
        } else {
            const float* pA = memory + (size_t)other0 * LL;
            const float* pB = memory + (size_t)other1 * LL;
            #pragma unroll 4
            for (int k4 = 32; k4 < 64; ++k4) {
                const float4 w  = w1p[k4 * LL + j];
                const float4 iA = *(const float4*)(pA + 4 * (k4 - 32));
                const float4 iB = *(const float4*)(pB + 4 * (k4 - 32));
                a0 = fmaf(w.x, iA.x, a0); a1 = fmaf(w.x, iB.x, a1);
                a0 = fmaf(w.y, iA.y, a0); a1 = fmaf(w.y, iB.y, a1);
                a0 = fmaf(w.z, iA.z, a0); a1 = fmaf(w.z, iB.z, a1);
                a0 = fmaf(w.w, iA.w, a0); a1 = fmaf(w.w, iB.w, a1);
            }
            #pragma unroll 4
            for (int k4 = 80; k4 < 96; ++k4) {
                const float4 w  = w1p[k4 * LL + j];
                const float4 iA = *(const float4*)(dA + 4 * (k4 - 64));
                const float4 iB = *(const float4*)(dB + 4 * (k4 - 64));
                a0 = fmaf(w.x, iA.x, a0); a1 = fmaf(w.x, iB.x, a1);
                a0 = fmaf(w.y, iA.y, a0); a1 = fmaf(w.y, iB.y, a1);
                a0 = fmaf(w.z, iA.z, a0); a1 = fmaf(w.z, iB.z, a1);
                a0 = fmaf(w.w, iA.w, a0); a1 = fmaf(w.w, iB.w, a1);
            }
            {   // k = 384: x input (w1p[96] has .y/.z/.w zero-padded)
                const float4 w = w1p[96 * LL + j];
                const float xA = x[(size_t)eg0 * NN + node0];
                const float xB = x[(size_t)eg1 * NN + node1];
                a0 = fmaf(w.x, xA, a0);
                a1 = fmaf(w.x, xB, a1);
            }
        }
        part1[g][0][j] = a0;
        part1[g][1][j] = a1;
    }
    __syncthreads();

    // Combine + bias + relu; thread (g,j) finishes edge e=g.
    h1[j][g] = fmaxf(part1[0][g][j] + part1[1][g][j] + b1[j], 0.0f);
    __syncthreads();

    // Layer 2 (packed w2, h1 via LDS): g0 -> k4 [0,16), g1 -> [16,32)
    {
        const int k40 = g * 16, k41 = k40 + 16;
        float a0 = 0.f, a1 = 0.f;
        #pragma unroll 4
        for (int k4 = k40; k4 < k41; ++k4) {
            const float4 w  = w2p[k4 * LL + j];
            const float4 h0 = *(const float4*)&h1[k4 * 4][0];
            const float4 h2 = *(const float4*)&h1[k4 * 4 + 2][0];
            a0 = fmaf(w.x, h0.x, a0); a1 = fmaf(w.x, h0.y, a1);
            a0 = fmaf(w.y, h0.z, a0); a1 = fmaf(w.y, h0.w, a1);
            a0 = fmaf(w.z, h2.x, a0); a1 = fmaf(w.z, h2.y, a1);
            a0 = fmaf(w.w, h2.z, a0); a1 = fmaf(w.w, h2.w, a1);
        }
        part2[g][0][j] = a0;
        part2[g][1][j] = a1;
    }
    __syncthreads();

    // Final message; atomic segment-sum. Thread (g,j) finishes edge e=g.
    {
        const int node = g ? node1 : node0;
        const float m = part2[0][g][j] + part2[1][g][j] + b2[j];
        atomicAdd(ws + OFF_MSG + (size_t)node * LL + j, m);
    }
    if (tid < EPB) {
        const int node = tid ? node1 : node0;
        const float old = atomicAdd(ws + OFF_CNT + node, 1.0f);
        if (old == 0.0f) {
            const int pos = atomicAdd((int*)ws + OFF_COUNT, 1);
            ((int*)ws)[OFF_LIST + pos] = node;
        }
    }
}

// ---------------------------------------------------------------------------
// GRU over the compact seen list. GPB=4 nodes/block, 256 blocks, gate-split.
// NO LDS staging: operands read at block-uniform scalar addresses; msg matvec
// accumulates on RAW msg_sum and scales by 1/cnt at the end (linearity).
// ---------------------------------------------------------------------------
__global__ __launch_bounds__(256) void gru_kernel(
    const float* __restrict__ memory,
    const float* __restrict__ bih, const float* __restrict__ bhh,
    const float* __restrict__ ws,   // read-only here
    float* __restrict__ out)
{
    const int tid = threadIdx.x;
    const int g = tid >> 7, j = tid & 127;
    const int scount = ((const int*)ws)[OFF_COUNT];
    const int base = blockIdx.x * GPB;
    if (base >= scount) return;
    const int nact = min(GPB, scount - base);

    __shared__ float gates[6][GPB][LL];      // 12 KB
    __shared__ int   nodes_sh[GPB];

    int nd[GPB];
    #pragma unroll
    for (int s = 0; s < GPB; ++s)
        nd[s] = (base + s < scount) ? ((const int*)ws)[OFF_LIST + base + s]
                                    : ((const int*)ws)[OFF_LIST + base];
    if (tid < GPB) nodes_sh[tid] = nd[tid];

    // Per-slot operand base (g0: raw msg_sum, g1: memory/h) + end-scale.
    const float* op0; const float* op1; const float* op2; const float* op3;
    float rc0 = 1.f, rc1 = 1.f, rc2 = 1.f, rc3 = 1.f;
    if (g == 0) {
        op0 = ws + OFF_MSG + (size_t)nd[0] * LL;
        op1 = ws + OFF_MSG + (size_t)nd[1] * LL;
        op2 = ws + OFF_MSG + (size_t)nd[2] * LL;
        op3 = ws + OFF_MSG + (size_t)nd[3] * LL;
        rc0 = 1.0f / ws[OFF_CNT + nd[0]];
        rc1 = 1.0f / ws[OFF_CNT + nd[1]];
        rc2 = 1.0f / ws[OFF_CNT + nd[2]];
        rc3 = 1.0f / ws[OFF_CNT + nd[3]];
    } else {
        op0 = memory + (size_t)nd[0] * LL;
        op1 = memory + (size_t)nd[1] * LL;
        op2 = memory + (size_t)nd[2] * LL;
        op3 = memory + (size_t)nd[3] * LL;
    }

    const float4* wp = (const float4*)(ws + (g ? OFF_WHHP : OFF_WIHP));
    float a0[GPB] = {}, a1[GPB] = {}, a2[GPB] = {};
    #pragma unroll 2
    for (int k4 = 0; k4 < NK4_2; ++k4) {
        const float4 w0 = wp[(0 * NK4_2 + k4) * LL + j];
        const float4 w1 = wp[(1 * NK4_2 + k4) * LL + j];
        const float4 w2 = wp[(2 * NK4_2 + k4) * LL + j];
        const float4 v0 = *(const float4*)(op0 + 4 * k4);
        const float4 v1 = *(const float4*)(op1 + 4 * k4);
        const float4 v2 = *(const float4*)(op2 + 4 * k4);
        const float4 v3 = *(const float4*)(op3 + 4 * k4);
        a0[0] = fmaf(w0.x, v0.x, a0[0]); a0[0] = fmaf(w0.y, v0.y, a0[0]);
        a0[0] = fmaf(w0.z, v0.z, a0[0]); a0[0] = fmaf(w0.w, v0.w, a0[0]);
        a1[0] = fmaf(w1.x, v0.x, a1[0]); a1[0] = fmaf(w1.y, v0.y, a1[0]);
        a1[0] = fmaf(w1.z, v0.z, a1[0]); a1[0] = fmaf(w1.w, v0.w, a1[0]);
        a2[0] = fmaf(w2.x, v0.x, a2[0]); a2[0] = fmaf(w2.y, v0.y, a2[0]);
        a2[0] = fmaf(w2.z, v0.z, a2[0]); a2[0] = fmaf(w2.w, v0.w, a2[0]);

        a0[1] = fmaf(w0.x, v1.x, a0[1]); a0[1] = fmaf(w0.y, v1.y, a0[1]);
        a0[1] = fmaf(w0.z, v1.z, a0[1]); a0[1] = fmaf(w0.w, v1.w, a0[1]);
        a1[1] = fmaf(w1.x, v1.x, a1[1]); a1[1] = fmaf(w1.y, v1.y, a1[1]);
        a1[1] = fmaf(w1.z, v1.z, a1[1]); a1[1] = fmaf(w1.w, v1.w, a1[1]);
        a2[1] = fmaf(w2.x, v1.x, a2[1]); a2[1] = fmaf(w2.y, v1.y, a2[1]);
        a2[1] = fmaf(w2.z, v1.z, a2[1]); a2[1] = fmaf(w2.w, v1.w, a2[1]);

        a0[2] = fmaf(w0.x, v2.x, a0[2]); a0[2] = fmaf(w0.y, v2.y, a0[2]);
        a0[2] = fmaf(w0.z, v2.z, a0[2]); a0[2] = fmaf(w0.w, v2.w, a0[2]);
        a1[2] = fmaf(w1.x, v2.x, a1[2]); a1[2] = fmaf(w1.y, v2.y, a1[2]);
        a1[2] = fmaf(w1.z, v2.z, a1[2]); a1[2] = fmaf(w1.w, v2.w, a1[2]);
        a2[2] = fmaf(w2.x, v2.x, a2[2]); a2[2] = fmaf(w2.y, v2.y, a2[2]);
        a2[2] = fmaf(w2.z, v2.z, a2[2]); a2[2] = fmaf(w2.w, v2.w, a2[2]);

        a0[3] = fmaf(w0.x, v3.x, a0[3]); a0[3] = fmaf(w0.y, v3.y, a0[3]);
        a0[3] = fmaf(w0.z, v3.z, a0[3]); a0[3] = fmaf(w0.w, v3.w, a0[3]);
        a1[3] = fmaf(w1.x, v3.x, a1[3]); a1[3] = fmaf(w1.y, v3.y, a1[3]);
        a1[3] = fmaf(w1.z, v3.z, a1[3]); a1[3] = fmaf(w1.w, v3.w, a1[3]);
        a2[3] = fmaf(w2.x, v3.x, a2[3]); a2[3] = fmaf(w2.y, v3.y, a2[3]);
        a2[3] = fmaf(w2.z, v3.z, a2[3]); a2[3] = fmaf(w2.w, v3.w, a2[3]);
    }
    if (g == 0) {
        a0[0] *= rc0; a1[0] *= rc0; a2[0] *= rc0;
        a0[1] *= rc1; a1[1] *= rc1; a2[1] *= rc1;
        a0[2] *= rc2; a1[2] *= rc2; a2[2] *= rc2;
        a0[3] *= rc3; a1[3] *= rc3; a2[3] *= rc3;
    }
    #pragma unroll
    for (int s = 0; s < GPB; ++s) {
        gates[g * 3 + 0][s][j] = a0[s];
        gates[g * 3 + 1][s][j] = a1[s];
        gates[g * 3 + 2][s][j] = a2[s];
    }
    __syncthreads();

    // Finalize: h re-read coalesced from global (L2 hit).
    const int total = nact * LL;
    for (int o = tid; o < total; o += 256) {
        const int s = o >> 7, jj = o & 127;
        const int node = nodes_sh[s];
        const float ir = gates[0][s][jj] + bih[jj];
        const float iz = gates[1][s][jj] + bih[LL + jj];
        const float inn = gates[2][s][jj] + bih[2 * LL + jj];
        const float hr = gates[3][s][jj] + bhh[jj];
        const float hz = gates[4][s][jj] + bhh[LL + jj];
        const float hn = gates[5][s][jj] + bhh[2 * LL + jj];
        const float r = 1.0f / (1.0f + __expf(-(ir + hr)));
        const float z = 1.0f / (1.0f + __expf(-(iz + hz)));
        const float n = tanhf(inn + r * hn);
        const float h = memory[(size_t)node * LL + jj];
        out[(size_t)node * LL + jj] = (1.0f - z) * n + z * h;
    }
}

// ---------------------------------------------------------------------------
extern "C" void kernel_launch(void* const* d_in, const int* in_sizes, int n_in,
                              void* d_out, int out_size, void* d_ws, size_t ws_size,
                              hipStream_t stream) {
    const float* x        = (const float*)d_in[0];
    const float* memory   = (const float*)d_in[1];
    const float* delta_t  = (const float*)d_in[2];
    const float* src_w1   = (const float*)d_in[3];
    const float* src_b1   = (const float*)d_in[4];
    const float* src_w2   = (const float*)d_in[5];
    const float* src_b2   = (const float*)d_in[6];
    const float* tar_w1   = (const float*)d_in[7];
    const float* tar_b1   = (const float*)d_in[8];
    const float* tar_w2   = (const float*)d_in[9];
    const float* tar_b2   = (const float*)d_in[10];
    const float* gru_wih  = (const float*)d_in[11];
    const float* gru_whh  = (const float*)d_in[12];
    const float* gru_bih  = (const float*)d_in[13];
    const float* gru_bhh  = (const float*)d_in[14];
    const int*   source   = (const int*)d_in[15];
    const int*   target   = (const int*)d_in[16];

    float* out = (float*)d_out;
    float* ws  = (float*)d_ws;

    // 1) prep: zero accumulators + pack all weights
    prep_kernel<<<512, 256, 0, stream>>>(
        src_w1, tar_w1, src_w2, tar_w2, gru_wih, gru_whh, ws);

    // 2) edge messages (512 blocks) + memory->out copy (32 blocks)
    edge_msg_kernel<<<544, 256, 0, stream>>>(
        x, memory, delta_t, src_b1, src_b2, tar_b1, tar_b2,
        source, target, ws, out);

    // 3) GRU over compact seen list
    gru_kernel<<<1024 / GPB, 256, 0, stream>>>(
        memory, gru_bih, gru_bhh, ws, out);
}